// Round 3
// baseline (151.532 us; speedup 1.0000x reference)
//
#include <hip/hip_runtime.h>

// Problem constants (B,S,D)=(2,2048,1024), H=16, DH=64, WINDOW=128
#define SQ      2048
#define NB      2
#define NH      16
#define DHD     64
#define WIN     128
#define DMODEL  1024
#define TRIPLE  3072

typedef __attribute__((ext_vector_type(8))) short  short8;
typedef __attribute__((ext_vector_type(4))) float  f32x4;

__device__ __forceinline__ unsigned short f2bf(float f) {
  unsigned u = __float_as_uint(f);
  u += 0x7fff + ((u >> 16) & 1);   // RNE
  return (unsigned short)(u >> 16);
}

// direct global->LDS DMA, 16 B per lane; LDS dest = wave-uniform base + lane*16
__device__ __forceinline__ void load_lds16(const void* g, void* l) {
  __builtin_amdgcn_global_load_lds(
      (const __attribute__((address_space(1))) unsigned int*)g,
      (__attribute__((address_space(3))) unsigned int*)l, 16, 0, 0);
}

// ------------------------------------------------- fused preprocessing (1 dispatch):
__global__ __launch_bounds__(256) void prep_kernel(
    const float* __restrict__ x, const float* __restrict__ w_qkv,
    const float* __restrict__ w_out,
    unsigned short* __restrict__ xb, unsigned short* __restrict__ wqkvT,
    unsigned short* __restrict__ woutT) {
  __shared__ float tile[32][33];
  int blk = blockIdx.x, tid = threadIdx.x;
  if (blk < 4096) {
    int idx = blk * 256 + tid;
    f32x4 v = ((const f32x4*)x)[idx];
    ushort4 o;
    o.x = f2bf(v[0]); o.y = f2bf(v[1]); o.z = f2bf(v[2]); o.w = f2bf(v[3]);
    ((ushort4*)xb)[idx] = o;
    return;
  }
  const float* in;
  unsigned short* out;
  int K = DMODEL, N, t;
  if (blk < 7168) { in = w_qkv; out = wqkvT; N = TRIPLE;  t = blk - 4096; }
  else            { in = w_out; out = woutT; N = DMODEL;  t = blk - 7168; }
  int ntiles = N / 32;
  int n0 = (t % ntiles) * 32, k0 = (t / ntiles) * 32;
  int tx = tid & 31, ty = tid >> 5;             // 32 x 8
#pragma unroll
  for (int r = 0; r < 4; ++r)
    tile[ty + 8 * r][tx] = in[(size_t)(k0 + ty + 8 * r) * N + (n0 + tx)];
  __syncthreads();
#pragma unroll
  for (int r = 0; r < 4; ++r)
    out[(size_t)(n0 + ty + 8 * r) * K + (k0 + tx)] = f2bf(tile[tx][ty + 8 * r]);
}

// ------------------------------------------------- C[M][N] = A[M][K]bf16 * Bt[N][K]bf16^T
// m97 structure + XOR chunk swizzle, 512 threads = 8 waves (4x2 MxN wave grid).
// (kept for fallback / reference)
template <bool BF16OUT>
__global__ __launch_bounds__(512) void gemm_bt_kernel(
    const unsigned short* __restrict__ A,
    const unsigned short* __restrict__ Bt,
    void* __restrict__ Cv,
    int M, int N, int K) {
  __shared__ short lsA[128 * 64];
  __shared__ short lsB[128 * 64];
  int tid  = threadIdx.x;
  int wave = tid >> 6, lane = tid & 63;
  int quad = lane >> 4, l16 = lane & 15;
  int wm = (wave & 3) * 32;
  int wn = (wave >> 2) * 64;
  int m0 = blockIdx.x * 128, n0 = blockIdx.y * 128;

  f32x4 acc[2][4] = {};

  const short* Ag = (const short*)A;
  const short* Bg = (const short*)Bt;

  int row8 = lane >> 3;
  int gcol = ((lane & 7) ^ row8) * 8;
  int sw = (l16 & 7) * 8;

  for (int k0 = 0; k0 < K; k0 += 64) {
    const short* Ab = Ag + (size_t)(m0 + wave * 16) * K + k0;
    const short* Bb = Bg + (size_t)(n0 + wave * 16) * K + k0;
#pragma unroll
    for (int inst = 0; inst < 2; ++inst) {
      int r = inst * 8 + row8;
      load_lds16(Ab + (size_t)r * K + gcol, &lsA[(wave * 16 + inst * 8) * 64]);
      load_lds16(Bb + (size_t)r * K + gcol, &lsB[(wave * 16 + inst * 8) * 64]);
    }
    __syncthreads();
#pragma unroll
    for (int ks = 0; ks < 2; ++ks) {
      int coff = ((ks * 32 + quad * 8) ^ sw);
      short8 af[2], bf[4];
#pragma unroll
      for (int t = 0; t < 2; ++t)
        af[t] = *(const short8*)(&lsA[(wm + t * 16 + l16) * 64 + coff]);
#pragma unroll
      for (int t = 0; t < 4; ++t)
        bf[t] = *(const short8*)(&lsB[(wn + t * 16 + l16) * 64 + coff]);
#pragma unroll
      for (int mt = 0; mt < 2; ++mt)
#pragma unroll
        for (int nt = 0; nt < 4; ++nt)
          acc[mt][nt] = __builtin_amdgcn_mfma_f32_16x16x32_bf16(
              af[mt], bf[nt], acc[mt][nt], 0, 0, 0);
    }
    __syncthreads();
  }
#pragma unroll
  for (int mt = 0; mt < 2; ++mt)
#pragma unroll
    for (int nt = 0; nt < 4; ++nt)
#pragma unroll
      for (int r = 0; r < 4; ++r) {
        int row = m0 + wm + mt * 16 + quad * 4 + r;
        int col = n0 + wn + nt * 16 + l16;
        if (BF16OUT)
          ((unsigned short*)Cv)[(size_t)row * N + col] = f2bf(acc[mt][nt][r]);
        else
          ((float*)Cv)[(size_t)row * N + col] = acc[mt][nt][r];
      }
}

// ------------------------------------------------- 128x64-tile variant for GEMM2.
template <bool BF16OUT>
__global__ __launch_bounds__(512) void gemm_bt_n64_kernel(
    const unsigned short* __restrict__ A,
    const unsigned short* __restrict__ Bt,
    void* __restrict__ Cv,
    int M, int N, int K) {
  __shared__ short lsA[128 * 64];
  __shared__ short lsB[64 * 64];
  int tid  = threadIdx.x;
  int wave = tid >> 6, lane = tid & 63;
  int quad = lane >> 4, l16 = lane & 15;
  int wm = wave * 16;
  int m0 = blockIdx.x * 128, n0 = blockIdx.y * 64;

  f32x4 acc[4] = {};

  const short* Ag = (const short*)A;
  const short* Bg = (const short*)Bt;

  int row8 = lane >> 3;
  int gcol = ((lane & 7) ^ row8) * 8;
  int sw = (l16 & 7) * 8;

  for (int k0 = 0; k0 < K; k0 += 64) {
    const short* Ab = Ag + (size_t)(m0 + wave * 16) * K + k0;
    const short* Bb = Bg + (size_t)(n0 + wave * 8) * K + k0;
#pragma unroll
    for (int inst = 0; inst < 2; ++inst) {
      int r = inst * 8 + row8;
      load_lds16(Ab + (size_t)r * K + gcol, &lsA[(wave * 16 + inst * 8) * 64]);
    }
    load_lds16(Bb + (size_t)row8 * K + gcol, &lsB[(wave * 8) * 64]);
    __syncthreads();
#pragma unroll
    for (int ks = 0; ks < 2; ++ks) {
      int coff = ((ks * 32 + quad * 8) ^ sw);
      short8 af = *(const short8*)(&lsA[(wm + l16) * 64 + coff]);
#pragma unroll
      for (int nt = 0; nt < 4; ++nt) {
        short8 bf = *(const short8*)(&lsB[(nt * 16 + l16) * 64 + coff]);
        acc[nt] = __builtin_amdgcn_mfma_f32_16x16x32_bf16(af, bf, acc[nt], 0, 0, 0);
      }
    }
    __syncthreads();
  }
#pragma unroll
  for (int nt = 0; nt < 4; ++nt)
#pragma unroll
    for (int r = 0; r < 4; ++r) {
      int row = m0 + wm + quad * 4 + r;
      int col = n0 + nt * 16 + l16;
      if (BF16OUT)
        ((unsigned short*)Cv)[(size_t)row * N + col] = f2bf(acc[nt][r]);
      else
        ((float*)Cv)[(size_t)row * N + col] = acc[nt][r];
    }
}

// ------------------------------------------------- 256^2 4-phase GEMM, deep prefetch v2.
// Identical body/barriers/LDS-map/epilogue to the round-0 version (correctness-proven);
// ONLY the prefetch issue points and vmcnt counts changed:
//  region deaths in tile t (buf c=t&1): A-h0 & all B die at p2-bar; A-h1 at p3-bar.
//  issues:  t.p0 -> ST_A(t+1, h1)  [dead since t-1.p3]
//           t.p3 -> ST_A(t+2,h0), ST_B(t+2,h0), ST_B(t+2,h1)  [dead at t.p2]
//  -> every load has ~4 phases in flight before first use (covers HBM ~900cyc).
//  waits (after MFMA, before phase-end barrier, so the wait overlaps compute):
//   end p0: need A-h1(t) [issued t-1.p0]; younger = 6(t+1 trio)+2(A-h1(t+1)) -> vmcnt(8)
//   end p3: need trio(t+1) [issued t-1.p3]; younger = 2(A-h1(t+1))+6(t+2 trio) -> vmcnt(8)
//  peeled tails: t=NT-2 p3 -> vmcnt(2); t=NT-1 p0 -> vmcnt(0).
template <int M, int N, int K, bool BF16OUT>
__global__ __launch_bounds__(512) void gemm8p_kernel(
    const unsigned short* __restrict__ A,
    const unsigned short* __restrict__ Bt,
    void* __restrict__ Cv) {
  constexpr int NT  = K / 64;        // 16 K-tiles
  constexpr int NBN = N / 256;
  __shared__ short lsA[2][256 * 64];
  __shared__ short lsB[2][256 * 64];

  const int tid  = threadIdx.x;
  const int wave = tid >> 6, lane = tid & 63;
  const int quad = lane >> 4, l16 = lane & 15;
  const int wm = (wave >> 2) * 128;       // 2 wave-rows of 128
  const int wn = (wave & 3) * 64;         // 4 wave-cols of 64

  // XCD-aware bijective swizzle (gridDim.x % 8 == 0: 192 blocks)
  const int nwg = gridDim.x;
  const int swz = ((int)blockIdx.x & 7) * (nwg >> 3) + ((int)blockIdx.x >> 3);
  const int m0 = (swz / NBN) * 256, n0 = (swz % NBN) * 256;

  const short* Ag = (const short*)A + (size_t)m0 * K;
  const short* Bg = (const short*)Bt + (size_t)n0 * K;

  const int r8 = lane >> 3;               // 0..7
  const int gc = ((lane & 7) ^ r8) * 8;   // swizzled source column (shorts)
  const int sw = (l16 & 7) * 8;           // frag-read XOR (shorts)
  const int wrow = wave * 16;             // wave's 16-row slice of each 128-row half

  f32x4 acc[8][4] = {};
  short8 bf[4];                           // B-frags live across phase pairs

#define SBAR0() __builtin_amdgcn_sched_barrier(0)
#define PHASE_BAR()                                   \
  do { SBAR0(); __builtin_amdgcn_s_barrier(); SBAR0(); } while (0)
#define LGKM0()                                       \
  do { asm volatile("s_waitcnt lgkmcnt(0)" ::: "memory"); SBAR0(); } while (0)
#define WAITV(n) asm volatile("s_waitcnt vmcnt(" #n ")" ::: "memory")
#define STAGE_HALF(lds, g)                                                        \
  do {                                                                            \
    load_lds16((g) + (size_t)(wrow + r8) * K + gc, (lds) + wrow * 64);            \
    load_lds16((g) + (size_t)(wrow + 8 + r8) * K + gc, (lds) + (wrow + 8) * 64);  \
  } while (0)
#define ST_A(t, h) STAGE_HALF(&lsA[(t) & 1][(h) * (128 * 64)],                    \
                              Ag + (size_t)((h) * 128) * K + (t) * 64)
#define ST_B(t, h) STAGE_HALF(&lsB[(t) & 1][(h) * (128 * 64)],                    \
                              Bg + (size_t)((h) * 128) * K + (t) * 64)

#define PH_READS_A(mh, ks)                                                        \
  { const int coff = ((ks) * 32 + quad * 8) ^ sw;                                 \
    _Pragma("unroll") for (int i_ = 0; i_ < 4; ++i_)                              \
      af[i_] = *(const short8*)(&la[(wm + (mh) * 64 + i_ * 16 + l16) * 64 + coff]); }
#define PH_READS_B(ks)                                                            \
  { const int coff = ((ks) * 32 + quad * 8) ^ sw;                                 \
    _Pragma("unroll") for (int n_ = 0; n_ < 4; ++n_)                              \
      bf[n_] = *(const short8*)(&lb[(wn + n_ * 16 + l16) * 64 + coff]); }
#define PH_MFMA(base)                                                             \
  __builtin_amdgcn_s_setprio(1);                                                  \
  _Pragma("unroll") for (int i_ = 0; i_ < 4; ++i_)                                \
    _Pragma("unroll") for (int n_ = 0; n_ < 4; ++n_)                              \
      acc[(base) + i_][n_] = __builtin_amdgcn_mfma_f32_16x16x32_bf16(             \
          af[i_], bf[n_], acc[(base) + i_][n_], 0, 0, 0);                         \
  __builtin_amdgcn_s_setprio(0);

#define TILE(t, DO_A1, DO_NX, W0, W3)                                             \
  {                                                                               \
    short* la = lsA[(t) & 1];                                                     \
    short* lb = lsB[(t) & 1];                                                     \
    short8 af[4];                                                                 \
    /* ---- p0: mh=0 ks=0 ---- */                                                 \
    PH_READS_A(0, 0); PH_READS_B(0);                                              \
    if (DO_A1) { ST_A((t) + 1, 1); }                                              \
    PHASE_BAR(); LGKM0();                                                         \
    PH_MFMA(0);                                                                   \
    W0;                                                                           \
    PHASE_BAR();                                                                  \
    /* ---- p1: mh=1 ks=0 ---- */                                                 \
    PH_READS_A(1, 0);                                                             \
    PHASE_BAR(); LGKM0();                                                         \
    PH_MFMA(4);                                                                   \
    PHASE_BAR();                                                                  \
    /* ---- p2: mh=0 ks=1 ---- */                                                 \
    PH_READS_A(0, 1); PH_READS_B(1);                                              \
    PHASE_BAR(); LGKM0();                                                         \
    PH_MFMA(0);                                                                   \
    PHASE_BAR();                                                                  \
    /* ---- p3: mh=1 ks=1 ---- */                                                 \
    PH_READS_A(1, 1);                                                             \
    if (DO_NX) { ST_A((t) + 2, 0); ST_B((t) + 2, 0); ST_B((t) + 2, 1); }          \
    PHASE_BAR(); LGKM0();                                                         \
    PH_MFMA(4);                                                                   \
    W3;                                                                           \
    PHASE_BAR();                                                                  \
  }

  // prologue: tile0 full (8 loads) + tile1 {A-h0, B-h0, B-h1} (6 loads).
  // A-h1(1) is issued at t=0.p0 per the steady-state schedule.
  ST_A(0, 0); ST_A(0, 1); ST_B(0, 0); ST_B(0, 1);
  ST_A(1, 0); ST_B(1, 0); ST_B(1, 1);
  WAITV(6);                    // tile0's 8 landed; tile1's 6 still in flight
  PHASE_BAR();

  TILE(0, true, true, ((void)0), WAITV(8));
  for (int t = 1; t <= NT - 3; ++t)
    TILE(t, true, true, WAITV(8), WAITV(8));
  TILE(NT - 2, true, false, WAITV(8), WAITV(2));
  TILE(NT - 1, false, false, WAITV(0), ((void)0));

#undef TILE
#undef PH_MFMA
#undef PH_READS_B
#undef PH_READS_A
#undef ST_B
#undef ST_A
#undef STAGE_HALF
#undef WAITV
#undef LGKM0
#undef PHASE_BAR
#undef SBAR0

  // epilogue (unchanged from the correctness-proven round-0 version)
#pragma unroll
  for (int m = 0; m < 8; ++m)
#pragma unroll
    for (int n = 0; n < 4; ++n)
#pragma unroll
      for (int r = 0; r < 4; ++r) {
        int row = m0 + wm + m * 16 + quad * 4 + r;
        int col = n0 + wn + n * 16 + l16;
        if (BF16OUT)
          ((unsigned short*)Cv)[(size_t)row * N + col] = f2bf(acc[m][n][r]);
        else
          ((float*)Cv)[(size_t)row * N + col] = acc[m][n][r];
      }
}

// ------------------------------------------------- MFMA flash attention v2 (bf16 in/out)
#define KSTR 72    // K tile row stride (shorts):     192 x 72
#define VSTR 200   // V^T tile row stride (shorts):    64 x 200
#define PSTR 72    // P tile row stride (shorts): 4 x (16 x 72)
__global__ __launch_bounds__(256) void attn_kernel(
    const unsigned short* __restrict__ qkvb,
    unsigned short* __restrict__ attnout) {
  __shared__ short Kl[192 * KSTR];
  __shared__ short Vt[64 * VSTR];
  __shared__ short Pl[4][16 * PSTR];

  int i0 = blockIdx.x * 64, h = blockIdx.y, b = blockIdx.z;
  int tid = threadIdx.x, wave = tid >> 6, lane = tid & 63;
  int quad = lane >> 4, l16 = lane & 15;
  const unsigned short* base = qkvb + (size_t)b * SQ * TRIPLE;

  short8 qa[2];
  {
    int qi = i0 + wave * 16 + l16;
    const unsigned short* qrow = base + (size_t)qi * TRIPLE + h * DHD;
    qa[0] = *(const short8*)(qrow + quad * 8);
    qa[1] = *(const short8*)(qrow + 32 + quad * 8);
  }

  int jbase = (i0 >= WIN) ? (i0 - WIN) : 0;
  int nch = (i0 + 64 - jbase) >> 6;        // 1..3 chunks of 64 keys

  int srow_ = tid >> 3;               // 0..31
  int scol_ = (tid & 7) * 8;          // 0..56
  for (int p = 0; p < 2 * nch; ++p) {
    int r = p * 32 + srow_;
    int j = jbase + r;
    const unsigned short* kr = base + (size_t)j * TRIPLE + DMODEL + h * DHD + scol_;
    *(short8*)(&Kl[r * KSTR + scol_]) = *(const short8*)kr;
    const unsigned short* vr = base + (size_t)j * TRIPLE + 2 * DMODEL + h * DHD + scol_;
    short8 vv = *(const short8*)vr;
#pragma unroll
    for (int e = 0; e < 8; ++e) {
      int d = scol_ + e;
      Vt[d * VSTR + (r ^ (((d >> 3) & 7) << 3))] = vv[e];
    }
  }
  __syncthreads();

  f32x4 o[4] = {};
  float mrow[4] = {-1e30f, -1e30f, -1e30f, -1e30f};
  float lrow[4] = {0.f, 0.f, 0.f, 0.f};
  int irow = i0 + wave * 16 + quad * 4;

  for (int c = 0; c < nch; ++c) {
    int jc = jbase + c * 64;

    f32x4 s[4] = {};
#pragma unroll
    for (int ks = 0; ks < 2; ++ks)
#pragma unroll
      for (int nt = 0; nt < 4; ++nt) {
        short8 bk = *(const short8*)(&Kl[(c * 64 + nt * 16 + l16) * KSTR + ks * 32 + quad * 8]);
        s[nt] = __builtin_amdgcn_mfma_f32_16x16x32_bf16(qa[ks], bk, s[nt], 0, 0, 0);
      }
#pragma unroll
    for (int nt = 0; nt < 4; ++nt)
#pragma unroll
      for (int r = 0; r < 4; ++r) {
        int i_ = irow + r;
        int j_ = jc + nt * 16 + l16;
        bool ok = (j_ <= i_) && (j_ > i_ - WIN);
        s[nt][r] = ok ? s[nt][r] * 0.125f : -1e30f;
      }
    float rm[4];
#pragma unroll
    for (int r = 0; r < 4; ++r)
      rm[r] = fmaxf(fmaxf(s[0][r], s[1][r]), fmaxf(s[2][r], s[3][r]));
#pragma unroll
    for (int off = 1; off < 16; off <<= 1)
#pragma unroll
      for (int r = 0; r < 4; ++r) rm[r] = fmaxf(rm[r], __shfl_xor(rm[r], off, 64));
    float al[4];
#pragma unroll
    for (int r = 0; r < 4; ++r) {
      float mn = fmaxf(mrow[r], rm[r]);
      al[r] = __expf(mrow[r] - mn);
      mrow[r] = mn;
    }
    f32x4 p[4];
#pragma unroll
    for (int nt = 0; nt < 4; ++nt)
#pragma unroll
      for (int r = 0; r < 4; ++r) p[nt][r] = __expf(s[nt][r] - mrow[r]);
    float rs[4];
#pragma unroll
    for (int r = 0; r < 4; ++r)
      rs[r] = (p[0][r] + p[1][r]) + (p[2][r] + p[3][r]);
#pragma unroll
    for (int off = 1; off < 16; off <<= 1)
#pragma unroll
      for (int r = 0; r < 4; ++r) rs[r] += __shfl_xor(rs[r], off, 64);
#pragma unroll
    for (int r = 0; r < 4; ++r) lrow[r] = lrow[r] * al[r] + rs[r];
#pragma unroll
    for (int nt = 0; nt < 4; ++nt)
#pragma unroll
      for (int r = 0; r < 4; ++r) o[nt][r] *= al[r];
#pragma unroll
    for (int nt = 0; nt < 4; ++nt)
#pragma unroll
      for (int r = 0; r < 4; ++r)
        Pl[wave][(quad * 4 + r) * PSTR + nt * 16 + l16] = f2bf(p[nt][r]);
    short8 pa[2];
    pa[0] = *(const short8*)(&Pl[wave][l16 * PSTR + quad * 8]);
    pa[1] = *(const short8*)(&Pl[wave][l16 * PSTR + 32 + quad * 8]);
#pragma unroll
    for (int ks = 0; ks < 2; ++ks)
#pragma unroll
      for (int nt = 0; nt < 4; ++nt) {
        int d2 = nt * 16 + l16;
        int vsw = ((d2 >> 3) & 7) << 3;
        short8 bv = *(const short8*)(
            &Vt[d2 * VSTR + ((c * 64 + ks * 32 + quad * 8) ^ vsw)]);
        o[nt] = __builtin_amdgcn_mfma_f32_16x16x32_bf16(pa[ks], bv, o[nt], 0, 0, 0);
      }
  }

  float inv[4];
#pragma unroll
  for (int r = 0; r < 4; ++r) inv[r] = 1.0f / lrow[r];
#pragma unroll
  for (int nt = 0; nt < 4; ++nt)
#pragma unroll
    for (int r = 0; r < 4; ++r) {
      int i_ = irow + r;
      int d_ = nt * 16 + l16;
      attnout[(size_t)(b * SQ + i_) * DMODEL + h * DHD + d_] = f2bf(o[nt][r] * inv[r]);
    }
}

// ----------------------------------------------------------------------------------
extern "C" void kernel_launch(void* const* d_in, const int* in_sizes, int n_in,
                              void* d_out, int out_size, void* d_ws, size_t ws_size,
                              hipStream_t stream) {
  const float* x     = (const float*)d_in[0];   // [2,2048,1024]
  const float* w_qkv = (const float*)d_in[1];   // [1024,3072]
  const float* w_out = (const float*)d_in[2];   // [1024,1024]
  float* out = (float*)d_out;                   // [2,2048,1024] fp32

  char* ws = (char*)d_ws;
  unsigned short* xb    = (unsigned short*)(ws);               //  8 MB  [4096][1024] bf16
  unsigned short* wqkvT = (unsigned short*)(ws + 8388608);     //  6 MB  [3072][1024] bf16
  unsigned short* woutT = (unsigned short*)(ws + 14680064);    //  2 MB  [1024][1024] bf16
  unsigned short* qkvb  = (unsigned short*)(ws + 16777216);    // 24 MB  [4096][3072] bf16
  unsigned short* attn  = (unsigned short*)(ws + 41943040);    //  8 MB  [4096][1024] bf16

  // 1. fused preprocessing (cast x + transpose both weights)
  prep_kernel<<<8192, 256, 0, stream>>>(x, w_qkv, w_out, xb, wqkvT, woutT);
  // 2. qkvb = xb @ wqkvT^T  (bf16 out) — 256^2 4-phase deep-prefetch, 192 blocks
  gemm8p_kernel<NB * SQ, TRIPLE, DMODEL, true>
      <<<(NB * SQ / 256) * (TRIPLE / 256), 512, 0, stream>>>(xb, wqkvT, qkvb);
  // 3. MFMA flash attention (single-stage union)
  attn_kernel<<<dim3(SQ / 64, NH, NB), 256, 0, stream>>>(qkvb, attn);
  // 4. out = attn @ woutT^T  (fp32 out) — 128x64 tiles, 512 blocks = 2/CU
  gemm_bt_n64_kernel<false><<<dim3((NB * SQ) / 128, DMODEL / 64), 512, 0, stream>>>(
      attn, woutT, out, NB * SQ, DMODEL, DMODEL);
}

// Round 4
// 142.994 us; speedup vs baseline: 1.0597x; 1.0597x over previous
//
#include <hip/hip_runtime.h>

// Problem constants (B,S,D)=(2,2048,1024), H=16, DH=64, WINDOW=128
#define SQ      2048
#define NB      2
#define NH      16
#define DHD     64
#define WIN     128
#define DMODEL  1024
#define TRIPLE  3072

typedef __attribute__((ext_vector_type(8))) short  short8;
typedef __attribute__((ext_vector_type(4))) float  f32x4;

__device__ __forceinline__ unsigned short f2bf(float f) {
  unsigned u = __float_as_uint(f);
  u += 0x7fff + ((u >> 16) & 1);   // RNE
  return (unsigned short)(u >> 16);
}

// direct global->LDS DMA, 16 B per lane; LDS dest = wave-uniform base + lane*16
__device__ __forceinline__ void load_lds16(const void* g, void* l) {
  __builtin_amdgcn_global_load_lds(
      (const __attribute__((address_space(1))) unsigned int*)g,
      (__attribute__((address_space(3))) unsigned int*)l, 16, 0, 0);
}

// ------------------------------------------------- fused preprocessing (1 dispatch):
// blocks [0,4096)            : cast x fp32 -> bf16 (1024 elems/block)
// blocks [4096,7168)         : transpose+cast w_qkv [1024][3072] -> [3072][1024]
// blocks [7168,8192)         : transpose+cast w_out [1024][1024] -> [1024][1024]
__global__ __launch_bounds__(256) void prep_kernel(
    const float* __restrict__ x, const float* __restrict__ w_qkv,
    const float* __restrict__ w_out,
    unsigned short* __restrict__ xb, unsigned short* __restrict__ wqkvT,
    unsigned short* __restrict__ woutT) {
  __shared__ float tile[32][33];
  int blk = blockIdx.x, tid = threadIdx.x;
  if (blk < 4096) {
    int idx = blk * 256 + tid;
    f32x4 v = ((const f32x4*)x)[idx];
    ushort4 o;
    o.x = f2bf(v[0]); o.y = f2bf(v[1]); o.z = f2bf(v[2]); o.w = f2bf(v[3]);
    ((ushort4*)xb)[idx] = o;
    return;
  }
  const float* in;
  unsigned short* out;
  int K = DMODEL, N, t;
  if (blk < 7168) { in = w_qkv; out = wqkvT; N = TRIPLE;  t = blk - 4096; }
  else            { in = w_out; out = woutT; N = DMODEL;  t = blk - 7168; }
  int ntiles = N / 32;
  int n0 = (t % ntiles) * 32, k0 = (t / ntiles) * 32;
  int tx = tid & 31, ty = tid >> 5;             // 32 x 8
#pragma unroll
  for (int r = 0; r < 4; ++r)
    tile[ty + 8 * r][tx] = in[(size_t)(k0 + ty + 8 * r) * N + (n0 + tx)];
  __syncthreads();
#pragma unroll
  for (int r = 0; r < 4; ++r)
    out[(size_t)(n0 + ty + 8 * r) * K + (k0 + tx)] = f2bf(tile[tx][ty + 8 * r]);
}

// ------------------------------------------------- C[M][N] = A[M][K]bf16 * Bt[N][K]bf16^T
// m97 structure + XOR chunk swizzle, 512 threads = 8 waves (4x2 MxN wave grid),
// each wave a 32x64 subtile (2x4 MFMA 16x16x32). 768 blocks for GEMM1 -> 3 blocks/CU,
// implicit wave-level overlap (m114). LDS slot (row, c) holds global chunk
// (row, c ^ (row&7)); frag reads hit slot (c ^ (l16&7)) -> 2-way aliasing (free).
// NOTE: 256^2 8-phase port tried twice (rounds 1,3): 45.9/47.4us, MfmaUtil ~20%,
// insensitive to prefetch depth -> structural (LDS/barrier serialization), closed.
template <bool BF16OUT>
__global__ __launch_bounds__(512) void gemm_bt_kernel(
    const unsigned short* __restrict__ A,
    const unsigned short* __restrict__ Bt,
    void* __restrict__ Cv,
    int M, int N, int K) {
  __shared__ short lsA[128 * 64];
  __shared__ short lsB[128 * 64];
  int tid  = threadIdx.x;
  int wave = tid >> 6, lane = tid & 63;
  int quad = lane >> 4, l16 = lane & 15;
  int wm = (wave & 3) * 32;           // 4 wave-rows of 32
  int wn = (wave >> 2) * 64;          // 2 wave-cols of 64
  int m0 = blockIdx.x * 128, n0 = blockIdx.y * 128;

  f32x4 acc[2][4] = {};

  const short* Ag = (const short*)A;
  const short* Bg = (const short*)Bt;

  int row8 = lane >> 3;                       // 0..7
  int gcol = ((lane & 7) ^ row8) * 8;         // swizzled source column (shorts)
  int sw = (l16 & 7) * 8;                     // frag-read XOR (shorts)

  for (int k0 = 0; k0 < K; k0 += 64) {
    // wave stages tile rows [16w, 16w+16) of both A and B (2 insts each)
    const short* Ab = Ag + (size_t)(m0 + wave * 16) * K + k0;
    const short* Bb = Bg + (size_t)(n0 + wave * 16) * K + k0;
#pragma unroll
    for (int inst = 0; inst < 2; ++inst) {
      int r = inst * 8 + row8;
      load_lds16(Ab + (size_t)r * K + gcol, &lsA[(wave * 16 + inst * 8) * 64]);
      load_lds16(Bb + (size_t)r * K + gcol, &lsB[(wave * 16 + inst * 8) * 64]);
    }
    __syncthreads();
#pragma unroll
    for (int ks = 0; ks < 2; ++ks) {
      int coff = ((ks * 32 + quad * 8) ^ sw);
      short8 af[2], bf[4];
#pragma unroll
      for (int t = 0; t < 2; ++t)
        af[t] = *(const short8*)(&lsA[(wm + t * 16 + l16) * 64 + coff]);
#pragma unroll
      for (int t = 0; t < 4; ++t)
        bf[t] = *(const short8*)(&lsB[(wn + t * 16 + l16) * 64 + coff]);
#pragma unroll
      for (int mt = 0; mt < 2; ++mt)
#pragma unroll
        for (int nt = 0; nt < 4; ++nt)
          acc[mt][nt] = __builtin_amdgcn_mfma_f32_16x16x32_bf16(
              af[mt], bf[nt], acc[mt][nt], 0, 0, 0);
    }
    __syncthreads();
  }
#pragma unroll
  for (int mt = 0; mt < 2; ++mt)
#pragma unroll
    for (int nt = 0; nt < 4; ++nt)
#pragma unroll
      for (int r = 0; r < 4; ++r) {
        int row = m0 + wm + mt * 16 + quad * 4 + r;
        int col = n0 + wn + nt * 16 + l16;
        if (BF16OUT)
          ((unsigned short*)Cv)[(size_t)row * N + col] = f2bf(acc[mt][nt][r]);
        else
          ((float*)Cv)[(size_t)row * N + col] = acc[mt][nt][r];
      }
}

// ------------------------------------------------- 128x64-tile variant for GEMM2.
// GEMM2 (M=4096,N=1024) at 128^2 tiles gives exactly 256 blocks = 1 block/CU;
// 128x64 tiles -> 512 blocks = 2 blocks/CU = 16 waves/CU, LDS 24 KiB.
template <bool BF16OUT>
__global__ __launch_bounds__(512) void gemm_bt_n64_kernel(
    const unsigned short* __restrict__ A,
    const unsigned short* __restrict__ Bt,
    void* __restrict__ Cv,
    int M, int N, int K) {
  __shared__ short lsA[128 * 64];
  __shared__ short lsB[64 * 64];
  int tid  = threadIdx.x;
  int wave = tid >> 6, lane = tid & 63;
  int quad = lane >> 4, l16 = lane & 15;
  int wm = wave * 16;                 // 8 wave-rows of 16
  int m0 = blockIdx.x * 128, n0 = blockIdx.y * 64;

  f32x4 acc[4] = {};

  const short* Ag = (const short*)A;
  const short* Bg = (const short*)Bt;

  int row8 = lane >> 3;                       // 0..7
  int gcol = ((lane & 7) ^ row8) * 8;         // swizzled source column (shorts)
  int sw = (l16 & 7) * 8;                     // frag-read XOR (shorts)

  for (int k0 = 0; k0 < K; k0 += 64) {
    const short* Ab = Ag + (size_t)(m0 + wave * 16) * K + k0;
    const short* Bb = Bg + (size_t)(n0 + wave * 8) * K + k0;
#pragma unroll
    for (int inst = 0; inst < 2; ++inst) {
      int r = inst * 8 + row8;
      load_lds16(Ab + (size_t)r * K + gcol, &lsA[(wave * 16 + inst * 8) * 64]);
    }
    load_lds16(Bb + (size_t)row8 * K + gcol, &lsB[(wave * 8) * 64]);
    __syncthreads();
#pragma unroll
    for (int ks = 0; ks < 2; ++ks) {
      int coff = ((ks * 32 + quad * 8) ^ sw);
      short8 af = *(const short8*)(&lsA[(wm + l16) * 64 + coff]);
#pragma unroll
      for (int nt = 0; nt < 4; ++nt) {
        short8 bf = *(const short8*)(&lsB[(nt * 16 + l16) * 64 + coff]);
        acc[nt] = __builtin_amdgcn_mfma_f32_16x16x32_bf16(af, bf, acc[nt], 0, 0, 0);
      }
    }
    __syncthreads();
  }
#pragma unroll
  for (int nt = 0; nt < 4; ++nt)
#pragma unroll
    for (int r = 0; r < 4; ++r) {
      int row = m0 + wm + quad * 4 + r;
      int col = n0 + nt * 16 + l16;
      if (BF16OUT)
        ((unsigned short*)Cv)[(size_t)row * N + col] = f2bf(acc[nt][r]);
      else
        ((float*)Cv)[(size_t)row * N + col] = acc[nt][r];
    }
}

// ------------------------------------------------- MFMA flash attention v3 (bf16 in/out)
// 128-query blocks (was 64): 512 blocks, 256 threads. Each wave owns two 16-row
// groups (g=0: +0, g=1: +64). The whole key union (<=256 rows) is staged ONCE per
// 128 queries (-33% staging vs v2), then chunks run barrier-free. Wave-uniform
// chunk skip: a 16-row group computes only chunks overlapping its causal window
// (jc <= ig+15 and jc+63 > ig-WIN) — removes fully-masked QK/softmax/PV work.
// All row strides ≡ 8 shorts (mod 64): same (free) bank behavior as proven v2.
// LDS: 36864 + 33792 + 9216 = 79872 B -> 2 blocks/CU.
#define KSTR 72    // K tile row stride (shorts):     256 x 72
#define VSTR 264   // V^T tile row stride (shorts):    64 x 264
#define PSTR 72    // P tile row stride (shorts): 4 x (16 x 72)
__global__ __launch_bounds__(256) void attn_kernel(
    const unsigned short* __restrict__ qkvb,
    unsigned short* __restrict__ attnout) {
  __shared__ short Kl[256 * KSTR];
  __shared__ short Vt[64 * VSTR];
  __shared__ short Pl[4][16 * PSTR];

  int i0 = blockIdx.x * 128, h = blockIdx.y, b = blockIdx.z;
  int tid = threadIdx.x, wave = tid >> 6, lane = tid & 63;
  int quad = lane >> 4, l16 = lane & 15;
  const unsigned short* base = qkvb + (size_t)b * SQ * TRIPLE;

  // Q A-frags for both groups (A[m=lane&15][k=quad*8+e]), held across the loop
  short8 qa[2][2];
#pragma unroll
  for (int g = 0; g < 2; ++g) {
    int qi = i0 + g * 64 + wave * 16 + l16;
    const unsigned short* qrow = base + (size_t)qi * TRIPLE + h * DHD;
    qa[g][0] = *(const short8*)(qrow + quad * 8);
    qa[g][1] = *(const short8*)(qrow + 32 + quad * 8);
  }

  int jbase = (i0 >= WIN) ? (i0 - WIN) : 0;
  int nch = (i0 + 128 - jbase) >> 6;        // 2 or 4 chunks of 64 keys

  // ---- stage the whole union: K row-major, V transposed (swizzled columns) ----
  int srow_ = tid >> 3;               // 0..31
  int scol_ = (tid & 7) * 8;          // 0..56
  for (int p = 0; p < 2 * nch; ++p) {
    int r = p * 32 + srow_;
    int j = jbase + r;
    const unsigned short* kr = base + (size_t)j * TRIPLE + DMODEL + h * DHD + scol_;
    *(short8*)(&Kl[r * KSTR + scol_]) = *(const short8*)kr;
    const unsigned short* vr = base + (size_t)j * TRIPLE + 2 * DMODEL + h * DHD + scol_;
    short8 vv = *(const short8*)vr;
#pragma unroll
    for (int e = 0; e < 8; ++e) {
      int d = scol_ + e;
      Vt[d * VSTR + (r ^ (((d >> 3) & 7) << 3))] = vv[e];
    }
  }
  __syncthreads();

  f32x4 o[2][4] = {};
  float mrow[2][4], lrow[2][4];
#pragma unroll
  for (int g = 0; g < 2; ++g)
#pragma unroll
    for (int r = 0; r < 4; ++r) { mrow[g][r] = -1e30f; lrow[g][r] = 0.f; }

  for (int c = 0; c < nch; ++c) {
    int jc = jbase + c * 64;
#pragma unroll
    for (int g = 0; g < 2; ++g) {
      int ig = i0 + g * 64 + wave * 16;        // group's first query row (wave-uniform)
      if (jc > ig + 15) continue;              // chunk entirely in the future
      if (jc + 63 <= ig - WIN) continue;       // chunk entirely expired
      int irow = ig + quad * 4;                // + r = query index of acc row r

      // ---- S = Q K^T over 64 keys (C-layout: row=quad*4+r, col tiles nt) ----
      f32x4 s[4] = {};
#pragma unroll
      for (int ks = 0; ks < 2; ++ks)
#pragma unroll
        for (int nt = 0; nt < 4; ++nt) {
          short8 bk = *(const short8*)(
              &Kl[(c * 64 + nt * 16 + l16) * KSTR + ks * 32 + quad * 8]);
          s[nt] = __builtin_amdgcn_mfma_f32_16x16x32_bf16(qa[g][ks], bk, s[nt], 0, 0, 0);
        }
      // ---- scale + window mask ----
#pragma unroll
      for (int nt = 0; nt < 4; ++nt)
#pragma unroll
        for (int r = 0; r < 4; ++r) {
          int i_ = irow + r;
          int j_ = jc + nt * 16 + l16;
          bool ok = (j_ <= i_) && (j_ > i_ - WIN);
          s[nt][r] = ok ? s[nt][r] * 0.125f : -1e30f;
        }
      // ---- online softmax over 64 cols (4 tiles x 16 lanes) ----
      float rm[4];
#pragma unroll
      for (int r = 0; r < 4; ++r)
        rm[r] = fmaxf(fmaxf(s[0][r], s[1][r]), fmaxf(s[2][r], s[3][r]));
#pragma unroll
      for (int off = 1; off < 16; off <<= 1)
#pragma unroll
        for (int r = 0; r < 4; ++r) rm[r] = fmaxf(rm[r], __shfl_xor(rm[r], off, 64));
      float al[4];
#pragma unroll
      for (int r = 0; r < 4; ++r) {
        float mn = fmaxf(mrow[g][r], rm[r]);
        al[r] = __expf(mrow[g][r] - mn);       // exp(0)=1 when both -1e30: safe
        mrow[g][r] = mn;
      }
      f32x4 p[4];
#pragma unroll
      for (int nt = 0; nt < 4; ++nt)
#pragma unroll
        for (int r = 0; r < 4; ++r) p[nt][r] = __expf(s[nt][r] - mrow[g][r]);
      float rs[4];
#pragma unroll
      for (int r = 0; r < 4; ++r)
        rs[r] = (p[0][r] + p[1][r]) + (p[2][r] + p[3][r]);
#pragma unroll
      for (int off = 1; off < 16; off <<= 1)
#pragma unroll
        for (int r = 0; r < 4; ++r) rs[r] += __shfl_xor(rs[r], off, 64);
#pragma unroll
      for (int r = 0; r < 4; ++r) lrow[g][r] = lrow[g][r] * al[r] + rs[r];
#pragma unroll
      for (int nt = 0; nt < 4; ++nt)
#pragma unroll
        for (int r = 0; r < 4; ++r) o[g][nt][r] *= al[r];
      // ---- P: C-layout -> LDS -> A-frags (wave-private; DS in-order per wave) ----
#pragma unroll
      for (int nt = 0; nt < 4; ++nt)
#pragma unroll
        for (int r = 0; r < 4; ++r)
          Pl[wave][(quad * 4 + r) * PSTR + nt * 16 + l16] = f2bf(p[nt][r]);
      short8 pa[2];
      pa[0] = *(const short8*)(&Pl[wave][l16 * PSTR + quad * 8]);
      pa[1] = *(const short8*)(&Pl[wave][l16 * PSTR + 32 + quad * 8]);
      // ---- O += P V  (B-frag = Vt[d=nt*16+l16][j=ks*32+quad*8], swizzled) ----
#pragma unroll
      for (int ks = 0; ks < 2; ++ks)
#pragma unroll
        for (int nt = 0; nt < 4; ++nt) {
          int d2 = nt * 16 + l16;
          int vsw = ((d2 >> 3) & 7) << 3;
          short8 bv = *(const short8*)(
              &Vt[d2 * VSTR + ((c * 64 + ks * 32 + quad * 8) ^ vsw)]);
          o[g][nt] = __builtin_amdgcn_mfma_f32_16x16x32_bf16(pa[ks], bv, o[g][nt], 0, 0, 0);
        }
    }
  }

  // ---- epilogue ----
#pragma unroll
  for (int g = 0; g < 2; ++g) {
    float inv[4];
#pragma unroll
    for (int r = 0; r < 4; ++r) inv[r] = 1.0f / lrow[g][r];
    int ig = i0 + g * 64 + wave * 16 + quad * 4;
#pragma unroll
    for (int nt = 0; nt < 4; ++nt)
#pragma unroll
      for (int r = 0; r < 4; ++r) {
        int i_ = ig + r;
        int d_ = nt * 16 + l16;
        attnout[(size_t)(b * SQ + i_) * DMODEL + h * DHD + d_] = f2bf(o[g][nt][r] * inv[r]);
      }
  }
}

// ----------------------------------------------------------------------------------
extern "C" void kernel_launch(void* const* d_in, const int* in_sizes, int n_in,
                              void* d_out, int out_size, void* d_ws, size_t ws_size,
                              hipStream_t stream) {
  const float* x     = (const float*)d_in[0];   // [2,2048,1024]
  const float* w_qkv = (const float*)d_in[1];   // [1024,3072]
  const float* w_out = (const float*)d_in[2];   // [1024,1024]
  float* out = (float*)d_out;                   // [2,2048,1024] fp32

  char* ws = (char*)d_ws;
  // workspace layout (48 MB total)
  unsigned short* xb    = (unsigned short*)(ws);               //  8 MB  [4096][1024] bf16
  unsigned short* wqkvT = (unsigned short*)(ws + 8388608);     //  6 MB  [3072][1024] bf16
  unsigned short* woutT = (unsigned short*)(ws + 14680064);    //  2 MB  [1024][1024] bf16
  unsigned short* qkvb  = (unsigned short*)(ws + 16777216);    // 24 MB  [4096][3072] bf16
  unsigned short* attn  = (unsigned short*)(ws + 41943040);    //  8 MB  [4096][1024] bf16

  // 1. fused preprocessing (cast x + transpose both weights)
  prep_kernel<<<8192, 256, 0, stream>>>(x, w_qkv, w_out, xb, wqkvT, woutT);
  // 2. qkvb = xb @ wqkvT^T   (bf16 out) — 128^2, 768 blocks = 3/CU (proven)
  gemm_bt_kernel<true><<<dim3((NB * SQ) / 128, TRIPLE / 128), 512, 0, stream>>>(
      xb, wqkvT, qkvb, NB * SQ, TRIPLE, DMODEL);
  // 3. MFMA flash attention — 128-query blocks, union staged once, chunk skip
  attn_kernel<<<dim3(SQ / 128, NH, NB), 256, 0, stream>>>(qkvb, attn);
  // 4. out = attn @ woutT^T  (fp32 out) — 128x64 tiles, 512 blocks = 2/CU
  gemm_bt_n64_kernel<false><<<dim3((NB * SQ) / 128, DMODEL / 64), 512, 0, stream>>>(
      attn, woutT, out, NB * SQ, DMODEL, DMODEL);
}